// Round 11
// baseline (43.202 us; speedup 1.0000x reference)
//
#include <hip/hip_runtime.h>

// Ray-sphere intersection: N rays x 64 moving spheres -> closest hit distance.
// x: (1, N, 7) f32 = [origin(3), t_ray(1), direction(3)]
// z: (1, 384) f32 = 64 spheres x [center(3), velocity(3)]
// out: mu (N) ++ sigma (N), f32
//
// R11: LDS-staged ray loads. The AoS 56B/ray layout made every prologue VMEM
// instruction scatter 64 lanes across ~56 cache lines (1 L1 tag-lookup per
// ~9B delivered); idle time ~13us was constant across R1-R9 compute variants
// and scaled with passes-over-x (R10). Stage: wave-linear coalesced dword
// loads (256B/instr contiguous) -> LDS at stride 15 dwords (gcd(15,32)=1 ->
// conflict-free b32 readback), then 1 ray/thread from LDS.
//
// FROZEN ARITHMETIC (R3/R5/R8-proven, scalar form):
//   oc = fmaf(v,t, c-o); b = fmaf(dx,ocx,fmaf(dy,ocy,dz*ocz));
//   csq = fmaf(ocx,ocx,fmaf(ocy,ocy,ocz*ocz)); disc = fmaf(b,b, 1.0f-csq);
//   sq = raw v_sqrt(disc) (disc<0 -> NaN -> compares false -> BIG);
//   r = t0>0 ? t0 : (t1>0 ? t1 : BIG); closest = fminf(closest, r).
// Unsigned-bit-min tails are BANNED (failed R4, R7).

constexpr float BIGF = 1e10f;
constexpr int BLK = 512;            // threads per block = rays per block
constexpr int RAY_STRIDE = 15;      // dwords per ray in LDS (7 used + 8 pad)

__global__ __launch_bounds__(BLK, 8) void ray_sphere_kernel(
    const float* __restrict__ x, const float* __restrict__ z,
    float* __restrict__ out, int N)
{
    __shared__ float lds[BLK * RAY_STRIDE];   // 30720 B

    const int t = threadIdx.x;
    const int n = blockIdx.x * BLK + t;       // this thread's ray

    // ---- stage this block's x-slice into LDS, coalesced ----
    // slice = x[block*3584 .. +3584); thread t handles i = t + 512k, k=0..6
    const float* xs = x + (long)blockIdx.x * (BLK * 7);
    #pragma unroll
    for (int k = 0; k < 7; ++k) {
        unsigned i = (unsigned)(k * BLK + t);     // < 3584
        float v = xs[i];                          // wave-linear: 256B/instr
        unsigned r = i / 7u;                      // magic-mul
        unsigned j = i - r * 7u;
        lds[r * RAY_STRIDE + j] = v;
    }
    __syncthreads();

    // ---- read own ray from LDS (stride 15 dwords: conflict-free) ----
    const float* my = lds + t * RAY_STRIDE;
    float ox = my[0], oy = my[1], oz = my[2], tr = my[3],
          dx = my[4], dy = my[5], dz = my[6];

    // normalize d: d / (sqrt(|d|^2) + 1e-12)   (FROZEN)
    {
        float n2 = fmaf(dx, dx, fmaf(dy, dy, dz * dz));
        float inv = __builtin_amdgcn_rcpf(__builtin_amdgcn_sqrtf(n2) + 1e-12f);
        dx *= inv; dy *= inv; dz *= inv;
    }

    float closest = BIGF;

    #pragma unroll 16
    for (int s = 0; s < 64; ++s) {
        const float* zs = z + s * 6;          // uniform -> s_load, SGPR
        float cx = zs[0], cy = zs[1], cz = zs[2];
        float vx = zs[3], vy = zs[4], vz = zs[5];

        // FROZEN chain
        float ocx = fmaf(vx, tr, cx - ox);
        float ocy = fmaf(vy, tr, cy - oy);
        float ocz = fmaf(vz, tr, cz - oz);
        float b   = fmaf(dx, ocx, fmaf(dy, ocy, dz * ocz));
        float csq = fmaf(ocx, ocx, fmaf(ocy, ocy, ocz * ocz));
        float disc = fmaf(b, b, 1.0f - csq);
        float sq = __builtin_amdgcn_sqrtf(disc);   // disc<0 -> NaN -> BIG
        float t0 = b - sq, t1 = b + sq;
        float r1 = (t1 > 0.0f) ? t1 : BIGF;
        float r  = (t0 > 0.0f) ? t0 : r1;
        closest = fminf(closest, r);
    }

    out[n]     = closest;    // contiguous dword stores, coalesced
    out[N + n] = 0.002f;
}

extern "C" void kernel_launch(void* const* d_in, const int* in_sizes, int n_in,
                              void* d_out, int out_size, void* d_ws, size_t ws_size,
                              hipStream_t stream) {
    const float* x = (const float*)d_in[0];
    const float* z = (const float*)d_in[1];
    float* out = (float*)d_out;
    int N = in_sizes[0] / 7;   // 1048576

    int blocks = N / BLK;      // 2048
    ray_sphere_kernel<<<blocks, BLK, 0, stream>>>(x, z, out, N);
}

// Round 12
// 35.564 us; speedup vs baseline: 1.2148x; 1.2148x over previous
//
#include <hip/hip_runtime.h>

// Ray-sphere intersection: N rays x 64 moving spheres -> closest hit distance.
// x: (1, N, 7) f32 = [origin(3), t_ray(1), direction(3)]
// z: (1, 384) f32 = 64 spheres x [center(3), velocity(3)]
// out: mu (N) ++ sigma (N), f32
//
// R12 = R11's LDS-coalesced x staging (killed the ~40% idle: VALUBusy 58->83)
//     + R8's v2f packed 2-ray core (lowest VALU issue count, ~23/ray-sphere).
// LDS stride 9 dwords/ray (7+2 pad): 512 rays * 36B = 18.4KB -> 8 blocks/CU
// (full occupancy; R11's 30.7KB allowed only 5). Readback: lane stride 18
// dwords, gcd(18,32)=2 -> 2-way bank aliasing = free.
//
// FROZEN ARITHMETIC (R3/R5/R8-proven, elementwise identical):
//   oc = fma(v,t, c-o); b = fma(dx,ocx,fma(dy,ocy,dz*ocz));
//   csq = fma(ocx,ocx,fma(ocy,ocy,ocz*ocz)); disc = fma(b,b, 1-csq);
//   sq = raw v_sqrt(disc) (disc<0 -> NaN -> compares false -> BIG);
//   r = t0>0 ? t0 : (t1>0 ? t1 : BIG); closest = fmin(closest, r).
// Unsigned-bit-min tails are BANNED (failed R4, R7).

typedef float v2f __attribute__((ext_vector_type(2)));

constexpr float BIGF = 1e10f;
constexpr int BLK = 256;     // threads per block
constexpr int RPB = 512;     // rays per block (2 per thread)
constexpr int STR = 9;       // dwords per ray in LDS (7 used + 2 pad)

__global__ __launch_bounds__(BLK, 8) void ray_sphere_kernel(
    const float* __restrict__ x, const float* __restrict__ z,
    float* __restrict__ out, int N)
{
    __shared__ float lds[RPB * STR];            // 18432 B

    const int t = threadIdx.x;
    const long blockRay0 = (long)blockIdx.x * RPB;

    // ---- stage this block's 3584 x-floats into LDS, coalesced ----
    const float* xs = x + blockRay0 * 7;
    #pragma unroll
    for (int k = 0; k < 14; ++k) {
        unsigned i = (unsigned)(k * BLK + t);   // < 3584, wave-linear
        float v = xs[i];                        // 256B contiguous per instr
        unsigned r = i / 7u;                    // magic-mul
        unsigned j = i - r * 7u;
        lds[r * STR + j] = v;
    }
    __syncthreads();

    // ---- read my 2 rays from LDS ----
    const float* r0 = lds + (2 * t) * STR;
    const float* r1 = r0 + STR;
    v2f ox = {r0[0], r1[0]}, oy = {r0[1], r1[1]}, oz = {r0[2], r1[2]};
    v2f tr = {r0[3], r1[3]};
    v2f dx = {r0[4], r1[4]}, dy = {r0[5], r1[5]}, dz = {r0[6], r1[6]};

    // normalize d: d / (sqrt(|d|^2) + 1e-12)   (FROZEN)
    {
        v2f n2 = __builtin_elementwise_fma(dx, dx,
                 __builtin_elementwise_fma(dy, dy, dz * dz));
        v2f inv;
        inv[0] = __builtin_amdgcn_rcpf(__builtin_amdgcn_sqrtf(n2[0]) + 1e-12f);
        inv[1] = __builtin_amdgcn_rcpf(__builtin_amdgcn_sqrtf(n2[1]) + 1e-12f);
        dx *= inv; dy *= inv; dz *= inv;
    }

    v2f closest = {BIGF, BIGF};

    #pragma unroll 16
    for (int s = 0; s < 64; ++s) {
        const float* zs = z + s * 6;            // uniform -> s_load, SGPR
        float cx = zs[0], cy = zs[1], cz = zs[2];
        float vx = zs[3], vy = zs[4], vz = zs[5];

        // oc = (c - o) + v * t                 (FROZEN)
        v2f ocx = __builtin_elementwise_fma((v2f){vx, vx}, tr, cx - ox);
        v2f ocy = __builtin_elementwise_fma((v2f){vy, vy}, tr, cy - oy);
        v2f ocz = __builtin_elementwise_fma((v2f){vz, vz}, tr, cz - oz);
        // b = d . oc                           (FROZEN)
        v2f b = __builtin_elementwise_fma(dx, ocx,
                __builtin_elementwise_fma(dy, ocy, dz * ocz));
        // csq = |oc|^2                         (FROZEN)
        v2f csq = __builtin_elementwise_fma(ocx, ocx,
                  __builtin_elementwise_fma(ocy, ocy, ocz * ocz));
        // disc = b^2 + (1 - csq)               (FROZEN)
        v2f disc = __builtin_elementwise_fma(b, b, (v2f){1.0f, 1.0f} - csq);

        // disc<0 -> NaN -> both compares below false -> BIG
        v2f sq;
        sq[0] = __builtin_amdgcn_sqrtf(disc[0]);
        sq[1] = __builtin_amdgcn_sqrtf(disc[1]);

        v2f t0 = b - sq;
        v2f t1 = b + sq;

        #pragma unroll
        for (int k = 0; k < 2; ++k) {
            float r1v = (t1[k] > 0.0f) ? t1[k] : BIGF;   // cmp + cndmask
            float rr  = (t0[k] > 0.0f) ? t0[k] : r1v;    // cmp + cndmask
            closest[k] = fminf(closest[k], rr);          // v_min
        }
    }

    long n0 = blockRay0 + 2 * t;
    *(float2*)(out + n0)     = make_float2(closest[0], closest[1]);
    *(float2*)(out + N + n0) = make_float2(0.002f, 0.002f);
}

extern "C" void kernel_launch(void* const* d_in, const int* in_sizes, int n_in,
                              void* d_out, int out_size, void* d_ws, size_t ws_size,
                              hipStream_t stream) {
    const float* x = (const float*)d_in[0];
    const float* z = (const float*)d_in[1];
    float* out = (float*)d_out;
    int N = in_sizes[0] / 7;   // 1048576

    int blocks = N / RPB;      // 2048
    ray_sphere_kernel<<<blocks, BLK, 0, stream>>>(x, z, out, N);
}